// Round 3
// baseline (5381.725 us; speedup 1.0000x reference)
//
#include <hip/hip_runtime.h>
#include <cstdint>
#include <cstddef>

// ===========================================================================
// QLSTMHybrid: LSTM (S=1024,B=256,D=128,H=256) + attention pooling (A=256)
//
//   k_pack  : repack Wf/Wi/Wg/Wo/Wa fp32 -> packed f16x2 (ws)
//   k_xproj : xproj[s,b,c] = x[s,b,:]@Wx[:,c]+bias[c] (f16, ws); c gate-major
//   k_recur : persistent, 256 WGs (1/CU, 1 batch elem) x 256 thr.
//             Thread t owns unit t's FOUR gate columns (t,t+256,t+512,t+768)
//             -> gate epilogue fully in-registers, ONE barrier/step
//             (double-buffered h in LDS).
//             Wh: pairs 0..99 in VGPRs (4x100 regs), pairs 100..127 in LDS
//             (stride 28 dw == -4 mod 32: proven 0-conflict b128 pattern).
//             R2 evidence: VGPR_Count=128 w/ 192-reg arrays => AGPR shuffling;
//             VALUBusy 3200cyc/step vs 1024 dot2 floor. Fix: 1 wave/SIMD,
//             512-reg budget via __launch_bounds__(256,1).
//   k_attn  : 4 S-chunks per batch elem (1024 WGs) -> partial (m,Z,acc)
//   k_attn2 : combine 4 partials -> ctx
//   k_bcast : d_out[s,b,h] = ctx[b,h]
//
// d_out scratch usage during the pipeline (floats):
//   [0, 33554432)          oseq f16 h-sequence (as uint16 x 67108864)
//   [33554432, 34340864)   attn partials m/Z/acc (3 x 262144 floats)
//   [67108864, 67239936)   hx, cx (final outputs)
//
// ws layout (bytes):            needs ws_size >= 538,050,560
#define WS_WHP   0           // uint32[128][1024]  524288
#define WS_WXP   524288      // uint32[64][1024]   262144
#define WS_WAP   786432      // uint32[128][256]   131072
#define WS_CTX   917504      // float [65536]      262144
#define WS_XPROJ 1179648     // f16   [262144][1024] 536870912
// ===========================================================================

typedef _Float16 h2_t __attribute__((ext_vector_type(2)));

static __device__ __forceinline__ float fdot2(uint32_t a, uint32_t b, float acc) {
#if __has_builtin(__builtin_amdgcn_fdot2)
    return __builtin_amdgcn_fdot2(__builtin_bit_cast(h2_t, a),
                                  __builtin_bit_cast(h2_t, b), acc, false);
#else
    union { uint32_t u; _Float16 f[2]; } ua, ub;
    ua.u = a; ub.u = b;
    return acc + (float)ua.f[0] * (float)ub.f[0] + (float)ua.f[1] * (float)ub.f[1];
#endif
}

static __device__ __forceinline__ uint32_t packh2(float x, float y) {
    h2_t v; v[0] = (_Float16)x; v[1] = (_Float16)y;
    return __builtin_bit_cast(uint32_t, v);
}
static __device__ __forceinline__ uint16_t f16b(float v) {
    _Float16 h = (_Float16)v; return __builtin_bit_cast(uint16_t, h);
}
static __device__ __forceinline__ float h16tof(uint16_t u) {
    return (float)__builtin_bit_cast(_Float16, u);
}
static __device__ __forceinline__ float sigm(float x) {
    return 1.0f / (1.0f + __expf(-x));
}
static __device__ __forceinline__ float tanh_fast(float x) {
    float ax = fabsf(x);
    float e = __expf(-2.0f * ax);
    float r = (1.0f - e) / (1.0f + e);
    return (x < 0.0f) ? -r : r;
}

// ---------------------------------------------------------------- k_pack ---
__global__ void k_pack(const float* __restrict__ Wf, const float* __restrict__ Wi,
                       const float* __restrict__ Wg2, const float* __restrict__ Wo,
                       const float* __restrict__ Wa,
                       uint32_t* __restrict__ whp, uint32_t* __restrict__ wxp,
                       uint32_t* __restrict__ wap) {
    int idx = blockIdx.x * 256 + threadIdx.x;
    if (idx < 131072) {                       // Wh pairs: rows 128..383 of W*
        int p = idx >> 10, c = idx & 1023;
        int g = c >> 8, u = c & 255;
        const float* W = (g == 0) ? Wf : (g == 1) ? Wi : (g == 2) ? Wg2 : Wo;
        whp[idx] = packh2(W[(128 + 2 * p) * 256 + u], W[(129 + 2 * p) * 256 + u]);
    } else if (idx < 196608) {                // Wx pairs: rows 0..127
        int j = idx - 131072;
        int p = j >> 10, c = j & 1023;
        int g = c >> 8, u = c & 255;
        const float* W = (g == 0) ? Wf : (g == 1) ? Wi : (g == 2) ? Wg2 : Wo;
        wxp[j] = packh2(W[(2 * p) * 256 + u], W[(2 * p + 1) * 256 + u]);
    } else if (idx < 229376) {                // Wa pairs
        int j = idx - 196608;
        int p = j >> 8, aa = j & 255;
        wap[j] = packh2(Wa[(2 * p) * 256 + aa], Wa[(2 * p + 1) * 256 + aa]);
    }
}

// --------------------------------------------------------------- k_xproj ---
// grid 2048 x 512; each WG does 128 rows of (262144 x 128) @ (128 x 1024)
__global__ __launch_bounds__(512) void k_xproj(
        const float* __restrict__ x,
        const float* __restrict__ bfp, const float* __restrict__ bip,
        const float* __restrict__ bgp, const float* __restrict__ bop,
        const uint32_t* __restrict__ wxp, uint16_t* __restrict__ xproj) {
    __shared__ uint32_t xs[512];              // 8 rows x 64 pairs
    int t = threadIdx.x;
    int c0 = t, c1 = t + 512;
    uint32_t wx0[64], wx1[64];
#pragma unroll
    for (int p = 0; p < 64; ++p) {
        wx0[p] = wxp[p * 1024 + c0];
        wx1[p] = wxp[p * 1024 + c1];
    }
    float bias0 = (t < 256) ? bfp[t] : bip[t - 256];   // cols 0..511  : f,i
    float bias1 = (t < 256) ? bgp[t] : bop[t - 256];   // cols 512..1023: g,o
    int srow = t >> 6, pp = t & 63;
    long row0 = (long)blockIdx.x * 128;
    for (int ch = 0; ch < 16; ++ch) {
        long rbase = row0 + ch * 8;
        const float2* xr = (const float2*)(x + (rbase + srow) * 128) + pp;
        float2 xv = *xr;
        __syncthreads();                      // prior chunk's reads done
        xs[srow * 64 + pp] = packh2(xv.x, xv.y);
        __syncthreads();
#pragma unroll 1
        for (int r = 0; r < 8; ++r) {
            const uint32_t* hrow = xs + r * 64;
            float a0 = 0.f, d0 = 0.f, a1 = 0.f, d1 = 0.f;
#pragma unroll
            for (int p = 0; p < 64; p += 4) {
                uint4 hv = *(const uint4*)(hrow + p);
                a0 = fdot2(wx0[p + 0], hv.x, a0); d0 = fdot2(wx0[p + 1], hv.y, d0);
                a0 = fdot2(wx0[p + 2], hv.z, a0); d0 = fdot2(wx0[p + 3], hv.w, d0);
                a1 = fdot2(wx1[p + 0], hv.x, a1); d1 = fdot2(wx1[p + 1], hv.y, d1);
                a1 = fdot2(wx1[p + 2], hv.z, a1); d1 = fdot2(wx1[p + 3], hv.w, d1);
            }
            size_t orow = (size_t)(rbase + r) * 1024;
            xproj[orow + c0] = f16b(a0 + d0 + bias0);
            xproj[orow + c1] = f16b(a1 + d1 + bias1);
        }
    }
}

// --------------------------------------------------------------- k_recur ---
// LDS dwords: wlds[1024][28] = 28672, hbuf0 = 128, hbuf1 = 128 -> 115712 B
#define RECUR_LDS 115712

__global__ __launch_bounds__(256, 1) void k_recur(
        const uint32_t* __restrict__ whp, const uint16_t* __restrict__ xproj,
        const int* __restrict__ mask, uint16_t* __restrict__ oseq,
        float* __restrict__ dout) {
    extern __shared__ uint32_t smem[];
    uint32_t* wlds  = smem;                   // pairs 100..127, stride 28 dw
    uint32_t* hbuf0 = smem + 28672;
    uint32_t* hbuf1 = smem + 28800;
    int t = threadIdx.x;
    int b = blockIdx.x;

    // stage LDS weight pairs 100..127 for all 1024 cols
    for (int p = 0; p < 28; ++p)
        for (int c = t; c < 1024; c += 256)
            wlds[c * 28 + p] = whp[(100 + p) * 1024 + c];
    if (t < 128) hbuf0[t] = 0u;               // h = 0

    uint32_t w0[100], w1[100], w2[100], w3[100];   // pairs 0..99, 4 gate cols
#pragma unroll
    for (int p = 0; p < 100; ++p) {
        const uint32_t* r = whp + p * 1024 + t;
        w0[p] = r[0]; w1[p] = r[256]; w2[p] = r[512]; w3[p] = r[768];
    }
    float c_state = 0.f, h_state = 0.f;
    const uint16_t* xp = xproj + b * 1024 + t;
    uint16_t* op = oseq + b * 256 + t;
    uint16_t xf = xp[0], xi = xp[256], xg = xp[512], xo = xp[768];
    int mv = mask[b];
    const uint32_t* wl = wlds + t * 28;       // +7168/+14336/+21504 dw for g=1..3
    __syncthreads();

    for (int s = 0; s < 1024; ++s) {
        const uint32_t* hb = (s & 1) ? hbuf1 : hbuf0;
        uint32_t*       hn = (s & 1) ? hbuf0 : hbuf1;
        float pf = h16tof(xf), pi = h16tof(xi), pg = h16tof(xg), po = h16tof(xo);
        float mcur = (float)mv;
        xp += 262144;
        if (s < 1023) {                       // prefetch step s+1
            xf = xp[0]; xi = xp[256]; xg = xp[512]; xo = xp[768];
            mv = mask[(s + 1) * 256 + b];
        }
        float f0 = 0.f, f1 = 0.f, i0 = 0.f, i1 = 0.f;
        float g0 = 0.f, g1 = 0.f, o0 = 0.f, o1 = 0.f;
        // LDS-resident pairs 100..127 (7 uint4 chunks per gate column)
#pragma unroll
        for (int j = 0; j < 7; ++j) {
            uint4 hv = *(const uint4*)(hb + 100 + 4 * j);
            uint4 wa = *(const uint4*)(wl + 4 * j);
            uint4 wb = *(const uint4*)(wl + 7168 + 4 * j);
            uint4 wc = *(const uint4*)(wl + 14336 + 4 * j);
            uint4 wd = *(const uint4*)(wl + 21504 + 4 * j);
            f0 = fdot2(wa.x, hv.x, f0); f1 = fdot2(wa.y, hv.y, f1);
            f0 = fdot2(wa.z, hv.z, f0); f1 = fdot2(wa.w, hv.w, f1);
            i0 = fdot2(wb.x, hv.x, i0); i1 = fdot2(wb.y, hv.y, i1);
            i0 = fdot2(wb.z, hv.z, i0); i1 = fdot2(wb.w, hv.w, i1);
            g0 = fdot2(wc.x, hv.x, g0); g1 = fdot2(wc.y, hv.y, g1);
            g0 = fdot2(wc.z, hv.z, g0); g1 = fdot2(wc.w, hv.w, g1);
            o0 = fdot2(wd.x, hv.x, o0); o1 = fdot2(wd.y, hv.y, o1);
            o0 = fdot2(wd.z, hv.z, o0); o1 = fdot2(wd.w, hv.w, o1);
        }
        // VGPR-resident pairs 0..99 (25 uint4 chunks of h)
#pragma unroll
        for (int j = 0; j < 25; ++j) {
            uint4 hv = *(const uint4*)(hb + 4 * j);
            int p = 4 * j;
            f0 = fdot2(w0[p + 0], hv.x, f0); f1 = fdot2(w0[p + 1], hv.y, f1);
            f0 = fdot2(w0[p + 2], hv.z, f0); f1 = fdot2(w0[p + 3], hv.w, f1);
            i0 = fdot2(w1[p + 0], hv.x, i0); i1 = fdot2(w1[p + 1], hv.y, i1);
            i0 = fdot2(w1[p + 2], hv.z, i0); i1 = fdot2(w1[p + 3], hv.w, i1);
            g0 = fdot2(w2[p + 0], hv.x, g0); g1 = fdot2(w2[p + 1], hv.y, g1);
            g0 = fdot2(w2[p + 2], hv.z, g0); g1 = fdot2(w2[p + 3], hv.w, g1);
            o0 = fdot2(w3[p + 0], hv.x, o0); o1 = fdot2(w3[p + 1], hv.y, o1);
            o0 = fdot2(w3[p + 2], hv.z, o0); o1 = fdot2(w3[p + 3], hv.w, o1);
        }
        pf += f0 + f1; pi += i0 + i1; pg += g0 + g1; po += o0 + o1;
        float fg = sigm(pf) * mcur + (1.0f - mcur);
        float ig = sigm(pi) * mcur;
        float gg = tanh_fast(pg) * mcur;
        float og = sigm(po) * mcur + (1.0f - mcur);
        c_state = fg * c_state + ig * gg;
        h_state = og * tanh_fast(c_state);
        uint16_t hbits = f16b(h_state);
        ((uint16_t*)hn)[t] = hbits;           // h for next step (f16)
        op[0] = hbits;                        // h sequence for attention
        op += 65536;
        __syncthreads();                      // single barrier (double-buffer)
    }
    dout[67108864 + b * 256 + t] = h_state;   // hx
    dout[67174400 + b * 256 + t] = c_state;   // cx
}

// ---------------------------------------------------------------- k_attn ---
// 1024 WGs: (b, chunk) = (blk>>2, blk&3); 256 s-steps each; partial m/Z/acc.
__global__ __launch_bounds__(256) void k_attn(
        const uint32_t* __restrict__ wap, const float* __restrict__ ba,
        const uint16_t* __restrict__ oseq, float* __restrict__ parts) {
    __shared__ uint32_t rb[2][128];
    int a = threadIdx.x;
    int b = blockIdx.x >> 2, ch = blockIdx.x & 3;
    uint32_t wa[128];
#pragma unroll
    for (int p = 0; p < 128; ++p) wa[p] = wap[p * 256 + a];
    float bias = ba[a];
    const uint32_t* orow = (const uint32_t*)oseq + b * 128 + (size_t)ch * 256 * 32768;
    if (a < 128) rb[0][a] = orow[a];
    __syncthreads();
    float m = -3.0e38f, Z = 0.f, acc = 0.f;
    for (int s = 0; s < 256; ++s) {
        uint32_t nxt = 0;
        if (s < 255 && a < 128) nxt = orow[32768 * (s + 1) + a];
        const uint32_t* row = rb[s & 1];
        float l0 = bias, l1 = 0.f, l2 = 0.f, l3 = 0.f;
#pragma unroll
        for (int p = 0; p < 128; p += 4) {
            uint4 hv = *(const uint4*)(row + p);
            l0 = fdot2(wa[p + 0], hv.x, l0);
            l1 = fdot2(wa[p + 1], hv.y, l1);
            l2 = fdot2(wa[p + 2], hv.z, l2);
            l3 = fdot2(wa[p + 3], hv.w, l3);
        }
        float l = (l0 + l1) + (l2 + l3);
        uint32_t pv = row[a >> 1];
        float hself = h16tof((a & 1) ? (uint16_t)(pv >> 16) : (uint16_t)(pv & 0xffffu));
        float m2 = fmaxf(m, l);
        float al = __expf(m - m2);
        float pr = __expf(l - m2);
        Z = Z * al + pr;
        acc = acc * al + pr * hself;
        m = m2;
        if (s < 255 && a < 128) rb[(s + 1) & 1][a] = nxt;
        __syncthreads();
    }
    int idx = ((b << 2) + ch) * 256 + a;
    parts[idx] = m;
    parts[262144 + idx] = Z;
    parts[524288 + idx] = acc;
}

// --------------------------------------------------------------- k_attn2 ---
__global__ void k_attn2(const float* __restrict__ parts, float* __restrict__ ctx) {
    int a = threadIdx.x, b = blockIdx.x;
    float mv[4], zv[4], av[4];
    float M = -3.0e38f;
#pragma unroll
    for (int c2 = 0; c2 < 4; ++c2) {
        int idx = ((b << 2) + c2) * 256 + a;
        mv[c2] = parts[idx];
        zv[c2] = parts[262144 + idx];
        av[c2] = parts[524288 + idx];
        M = fmaxf(M, mv[c2]);
    }
    float Z = 0.f, A = 0.f;
#pragma unroll
    for (int c2 = 0; c2 < 4; ++c2) {
        float e = __expf(mv[c2] - M);
        Z += zv[c2] * e;
        A += av[c2] * e;
    }
    ctx[b * 256 + a] = A / Z;
}

// --------------------------------------------------------------- k_bcast ---
// output 0 = 67,108,864 floats = 16,777,216 float4 -> 65536 blocks x 256 thr
__global__ void k_bcast(const float4* __restrict__ ctx4, float4* __restrict__ out4) {
    int i = blockIdx.x * 256 + threadIdx.x;
    out4[i] = ctx4[i & 16383];                // 16384 float4 per s-slice
}

// ===========================================================================
extern "C" void kernel_launch(void* const* d_in, const int* in_sizes, int n_in,
                              void* d_out, int out_size, void* d_ws, size_t ws_size,
                              hipStream_t stream) {
    const float* x    = (const float*)d_in[0];
    const int*   mask = (const int*)d_in[1];
    const float* Wf   = (const float*)d_in[2];
    const float* bf   = (const float*)d_in[3];
    const float* Wi   = (const float*)d_in[4];
    const float* bi   = (const float*)d_in[5];
    const float* Wg   = (const float*)d_in[6];
    const float* bg   = (const float*)d_in[7];
    const float* Wo   = (const float*)d_in[8];
    const float* bo   = (const float*)d_in[9];
    const float* Wa   = (const float*)d_in[10];
    const float* ba   = (const float*)d_in[11];
    float* out = (float*)d_out;
    char*  ws  = (char*)d_ws;

    uint32_t* whp   = (uint32_t*)(ws + WS_WHP);
    uint32_t* wxp   = (uint32_t*)(ws + WS_WXP);
    uint32_t* wap   = (uint32_t*)(ws + WS_WAP);
    float*    ctx   = (float*)(ws + WS_CTX);
    uint16_t* xproj = (uint16_t*)(ws + WS_XPROJ);
    uint16_t* oseq  = (uint16_t*)d_out;       // f16 h-seq scratch inside d_out
    float*    parts = (float*)d_out + 33554432;   // attn partials (free region)

    (void)in_sizes; (void)n_in; (void)out_size; (void)ws_size;

    hipFuncSetAttribute((const void*)k_recur,
                        hipFuncAttributeMaxDynamicSharedMemorySize, RECUR_LDS);

    k_pack<<<896, 256, 0, stream>>>(Wf, Wi, Wg, Wo, Wa, whp, wxp, wap);
    k_xproj<<<2048, 512, 0, stream>>>(x, bf, bi, bg, bo, wxp, xproj);
    k_recur<<<256, 256, RECUR_LDS, stream>>>(whp, xproj, mask, oseq, out);
    k_attn<<<1024, 256, 0, stream>>>(wap, ba, oseq, parts);
    k_attn2<<<256, 256, 0, stream>>>(parts, ctx);
    k_bcast<<<65536, 256, 0, stream>>>((const float4*)ctx, (float4*)out);
}